// Round 9
// baseline (1400.081 us; speedup 1.0000x reference)
//
#include <hip/hip_runtime.h>
#include <hip/hip_bf16.h>
#include <hip/hip_fp16.h>

#define E_ 16
#define T_ 128

typedef _Float16 h2_t __attribute__((ext_vector_type(2)));

__device__ __forceinline__ float fdot2u(uint32_t w, uint32_t h, float acc) {
#if __has_builtin(__builtin_amdgcn_fdot2)
  return __builtin_amdgcn_fdot2(__builtin_bit_cast(h2_t, w),
                                __builtin_bit_cast(h2_t, h), acc, false);
#else
  h2_t wv = __builtin_bit_cast(h2_t, w), hv = __builtin_bit_cast(h2_t, h);
  return acc + (float)wv.x * (float)hv.x + (float)wv.y * (float)hv.y;
#endif
}

__device__ __forceinline__ uint32_t rdlane(uint32_t v, int l) {
  return (uint32_t)__builtin_amdgcn_readlane((int)v, l);
}

__device__ __forceinline__ uint32_t packh2(float a, float b) {
  h2_t p; p.x = (_Float16)a; p.y = (_Float16)b;
  return __builtin_bit_cast(uint32_t, p);
}

__device__ __forceinline__ float apply_act(float v, int act) {
  if (act == 1) return tanhf(v);
  if (act == 2) { // jax.nn.gelu approximate=True
    const float c = 0.7978845608028654f;
    return 0.5f * v * (1.0f + tanhf(c * (v + 0.044715f * v * v * v)));
  }
  return v;
}

// ---- skinny GEMM: C[128,N] = act(A[128,K] @ W[K,N] + bias), batched over e (grid.y), split-K (grid.z) ----
__global__ void __launch_bounds__(256) gemm_skinny(
    const float* __restrict__ A, const float* __restrict__ W,
    const float* __restrict__ bias, float* __restrict__ C, float* __restrict__ part,
    int N, int K, int lda, int ldc,
    long sAe, long sWe, long sBe, long sCe,
    int S, int act)
{
  int n0 = blockIdx.x * 64;
  int e  = blockIdx.y;
  int s  = blockIdx.z;
  const float* Ae = A + (long)e * sAe;
  const float* We = W + (long)e * sWe + n0;
  int kper = K / S;
  int kb = s * kper, ke = kb + kper;

  __shared__ float As[32][132];   // A-chunk transposed: As[kk][m], pad 4
  __shared__ float Ws[32][68];    // W-chunk: Ws[kk][n], pad 4
  int tid = threadIdx.x;
  int tn = tid & 15, tm = tid >> 4;
  float acc[8][4];
  #pragma unroll
  for (int i = 0; i < 8; ++i)
    #pragma unroll
    for (int j = 0; j < 4; ++j) acc[i][j] = 0.f;

  for (int k0 = kb; k0 < ke; k0 += 32) {
    #pragma unroll
    for (int i = 0; i < 4; ++i) {
      int li = i * 1024 + tid * 4;
      int r = li >> 5, kk = li & 31;
      float4 a4 = *(const float4*)(Ae + (long)r * lda + k0 + kk);
      As[kk+0][r] = a4.x; As[kk+1][r] = a4.y; As[kk+2][r] = a4.z; As[kk+3][r] = a4.w;
    }
    #pragma unroll
    for (int i = 0; i < 2; ++i) {
      int li = i * 1024 + tid * 4;
      int kk = li >> 6, j = li & 63;
      *(float4*)&Ws[kk][j] = *(const float4*)(We + (long)(k0 + kk) * N + j);
    }
    __syncthreads();
    #pragma unroll
    for (int kk = 0; kk < 32; ++kk) {
      float4 a0 = *(const float4*)&As[kk][tm*8];
      float4 a1 = *(const float4*)&As[kk][tm*8+4];
      float4 w4 = *(const float4*)&Ws[kk][tn*4];
      float av[8] = {a0.x,a0.y,a0.z,a0.w,a1.x,a1.y,a1.z,a1.w};
      float wv[4] = {w4.x,w4.y,w4.z,w4.w};
      #pragma unroll
      for (int i2 = 0; i2 < 8; ++i2)
        #pragma unroll
        for (int j2 = 0; j2 < 4; ++j2)
          acc[i2][j2] = fmaf(av[i2], wv[j2], acc[i2][j2]);
    }
    __syncthreads();
  }

  if (S == 1) {
    #pragma unroll
    for (int i2 = 0; i2 < 8; ++i2) {
      int r = tm * 8 + i2;
      float4 o; float* op = (float*)&o;
      #pragma unroll
      for (int j2 = 0; j2 < 4; ++j2)
        op[j2] = apply_act(acc[i2][j2] + bias[(long)e*sBe + n0 + tn*4 + j2], act);
      *(float4*)(C + (long)e*sCe + (long)r*ldc + n0 + tn*4) = o;
    }
  } else {
    float* pp = part + ((long)(s * gridDim.y + e) * 128) * N;
    #pragma unroll
    for (int i2 = 0; i2 < 8; ++i2) {
      int r = tm * 8 + i2;
      float4 o; float* op = (float*)&o;
      #pragma unroll
      for (int j2 = 0; j2 < 4; ++j2) op[j2] = acc[i2][j2];
      *(float4*)(pp + (long)r * N + n0 + tn*4) = o;
    }
  }
}

// reduce split-K partials + bias + act -> C
__global__ void __launch_bounds__(256) reduce_ep(
    const float* __restrict__ part, const float* __restrict__ bias, float* __restrict__ C,
    int S, int N, int ldc, long sBe, long sCe, int act, int total, int Eb)
{
  int idx = blockIdx.x * 256 + threadIdx.x;
  if (idx >= total) return;
  int n = idx % N;
  int r = (idx / N) & 127;
  int e = idx / (N * 128);
  long sstride = (long)Eb * 128 * N;
  float v = 0.f;
  for (int s = 0; s < S; ++s) v += part[s * sstride + ((long)e * 128 + r) * N + n];
  v = apply_act(v + bias[(long)e * sBe + n], act);
  C[(long)e * sCe + (long)r * ldc + n] = v;
}

// ---- sequential RNN layer: h[t] = tanh(P[t] + h[t-1] @ Wh) ----
// ONE workgroup per encoder, block = 1024 (16 waves), 1 WG/CU.
// Wave w: K-quarter kq = w>>2 (wave-uniform), column group colg = w&3;
// thread owns cols c0 = colg*128 + 2*lane, c0+1.
// Weight pairs/thread = 64 kpl x 2 cols = 128 uints: 46 kpl (92 regs) VGPR,
// 18 kpl (36 uints) LDS (147456 B, static).
// REGISTER BUDGET: the allocator's default heuristic hard-targets
// 65536/block_threads VGPRs (observed: 512->128, 1024->64 across R2-R8,
// immune to __launch_bounds__, amdgpu_waves_per_eu, and static-LDS
// occupancy evidence) and spills ~52 weight uints/thread to scratch
// (VGPR_Count=64, +5 MB WRITE_SIZE, ~2.3 us/step). amdgpu_num_vgpr(128)
// sets the backend's allocation target DIRECTLY. 128 regs x 16 waves x
// 64 lanes x 4 B = 512 KB = exactly the CU register file at 1 WG/CU;
// kernel needs ~112.
// h broadcast: one ds_read_b32/thread + v_readlane (SGPR operand of
// v_dot2_f32_f16); each broadcast pair feeds 2 dot2 (2 cols).
// Cross-quarter reduce: kq 1..3 write float2 partials to LDS; kq 0 sums +
// tanh + writes h. 2 barriers/step.
#define RNN_NV 46   // kpl in VGPRs (x2 cols = 92 regs)
#define RNN_NG 9    // uint4 LDS groups (18 kpl -> 36 uints/thread)

__global__ void
__attribute__((amdgpu_flat_work_group_size(1024, 1024)))
__attribute__((amdgpu_waves_per_eu(4, 4)))
__attribute__((amdgpu_num_vgpr(128)))
rnn_seq(
    const float* __restrict__ P,     // [T][E][512], pre-activation incl. bias
    const float* __restrict__ Wh,    // + e*sWe : [512][512]
    float* __restrict__ H,           // (t*E+e)*1536 + col  (layer offset applied by caller)
    long sWe)
{
  __shared__ uint32_t lw[RNN_NG * 4096];   // 147,456 B
  __shared__ uint32_t hbuf[256];           //   1,024 B (512 fp16)
  __shared__ float    red[3 * 512];        //   6,144 B

  int tid  = threadIdx.x;
  int lane = tid & 63;
  int wid  = tid >> 6;
  int kq   = wid >> 2;                 // K-quarter 0..3 (wave-uniform)
  int colg = wid & 3;
  int c0   = colg * 128 + lane * 2;    // this thread's two columns
  int e    = blockIdx.x;

  const float* W = Wh + (long)e * sWe;  // element (k,c) at W[k*512 + c]

  // kpl q covers k = kq*128 + 2q, 2q+1 ; w0=col c0, w1=col c0+1
  uint32_t w0[RNN_NV], w1[RNN_NV];
  #pragma unroll
  for (int q = 0; q < RNN_NV; ++q) {
    int k = kq * 128 + 2 * q;
    float2 ra = *(const float2*)(W + (long)k * 512 + c0);
    float2 rb = *(const float2*)(W + (long)(k + 1) * 512 + c0);
    w0[q] = packh2(ra.x, rb.x);
    w1[q] = packh2(ra.y, rb.y);
  }
  for (int g = 0; g < RNN_NG; ++g) {
    int k = kq * 128 + 2 * (RNN_NV + 2 * g);
    float2 ra = *(const float2*)(W + (long)(k + 0) * 512 + c0);
    float2 rb = *(const float2*)(W + (long)(k + 1) * 512 + c0);
    float2 rc = *(const float2*)(W + (long)(k + 2) * 512 + c0);
    float2 rd = *(const float2*)(W + (long)(k + 3) * 512 + c0);
    uint4 v;
    v.x = packh2(ra.x, rb.x);   // kpl RNN_NV+2g,   col c0
    v.y = packh2(ra.y, rb.y);   //                  col c0+1
    v.z = packh2(rc.x, rd.x);   // kpl RNN_NV+2g+1, col c0
    v.w = packh2(rc.y, rd.y);   //                  col c0+1
    *(uint4*)(lw + ((long)g * 1024 + tid) * 4) = v;
  }
  if (tid < 256) hbuf[tid] = 0;   // h(-1) = 0
  __syncthreads();

  for (int t = 0; t < T_; ++t) {
    // issue P load early (kq==0 only) — latency hides under the dot phase
    float2 pv = make_float2(0.f, 0.f);
    if (kq == 0) pv = *(const float2*)(P + ((long)t * E_ + e) * 512 + c0);
    uint32_t hr = hbuf[kq * 64 + lane];   // pair kq*64+lane = h[2P], h[2P+1]
    float a0 = 0.f, a1 = 0.f;
    #pragma unroll
    for (int L = 0; L < RNN_NV; ++L) {
      uint32_t hb = rdlane(hr, L);
      a0 = fdot2u(w0[L], hb, a0);
      a1 = fdot2u(w1[L], hb, a1);
    }
    #pragma unroll
    for (int g = 0; g < RNN_NG; ++g) {
      uint4 v = *(const uint4*)(lw + (g * 1024 + tid) * 4);
      uint32_t hb0 = rdlane(hr, RNN_NV + 2 * g);
      uint32_t hb1 = rdlane(hr, RNN_NV + 2 * g + 1);
      a0 = fdot2u(v.x, hb0, a0);
      a1 = fdot2u(v.y, hb0, a1);
      a0 = fdot2u(v.z, hb1, a0);
      a1 = fdot2u(v.w, hb1, a1);
    }
    if (kq) *(float2*)(red + (kq - 1) * 512 + c0) = make_float2(a0, a1);
    __syncthreads();                 // partials ready; all hbuf reads done
    if (kq == 0) {
      float v0 = a0 + red[c0]     + red[512 + c0]     + red[1024 + c0]     + pv.x;
      float v1 = a1 + red[c0 + 1] + red[512 + c0 + 1] + red[1024 + c0 + 1] + pv.y;
      v0 = tanhf(v0); v1 = tanhf(v1);
      *(float2*)(H + ((long)t * E_ + e) * 1536 + c0) = make_float2(v0, v1);
      hbuf[colg * 64 + lane] = packh2(v0, v1);
    }
    __syncthreads();                 // new h visible for next step
  }
}

extern "C" void kernel_launch(void* const* d_in, const int* in_sizes, int n_in,
                              void* d_out, int out_size, void* d_ws, size_t ws_size,
                              hipStream_t stream)
{
  const float* x      = (const float*)d_in[0];
  const float* W_in0  = (const float*)d_in[1];
  const float* Wh0    = (const float*)d_in[2];
  const float* b0     = (const float*)d_in[3];
  const float* W_inr  = (const float*)d_in[4];
  const float* Wh_r   = (const float*)d_in[5];
  const float* b_r    = (const float*)d_in[6];
  const float* W_ff1  = (const float*)d_in[7];
  const float* b_ff1  = (const float*)d_in[8];
  const float* W_ff2  = (const float*)d_in[9];
  const float* b_ff2  = (const float*)d_in[10];
  const float* W_d0   = (const float*)d_in[11];
  const float* b_d0   = (const float*)d_in[12];
  const float* W_dmid = (const float*)d_in[13];
  const float* b_dmid = (const float*)d_in[14];
  const float* W_dout = (const float*)d_in[15];
  const float* b_dout = (const float*)d_in[16];
  float* ws = (float*)d_ws;

  // workspace layout (floats)
  float* h    = ws;                    // [T][E][3][512]  3,145,728
  float* P    = ws + 3145728;          // [T][E][512]     1,048,576
  float* FF   = ws + 4194304;          // [T][E][2048]    4,194,304
  float* ENC  = ws + 8388608;          // [T][E*512]      1,048,576
  float* Z0   = ws + 9437184;          // [128][2048]       262,144
  float* Z1   = ws + 9699328;
  float* Z2   = ws + 9961472;
  float* PART = ws + 10223616;         // split-K partials 2,097,152

  (void)in_sizes; (void)n_in; (void)out_size; (void)ws_size;

  dim3 blk(256);

  // P = x @ W_in0 + b0
  gemm_skinny<<<dim3(8,16,1), blk, 0, stream>>>(x, W_in0, b0, P, PART,
      512, 32, 32, 8192, 0L, 16384L, 512L, 512L, 1, 0);
  // layer 0 recurrence
  rnn_seq<<<dim3(16), dim3(1024), 0, stream>>>(P, Wh0, h, 262144L);
  // P = h0 @ W_in_rest[:,0] + b_rest[:,0]
  gemm_skinny<<<dim3(8,16,1), blk, 0, stream>>>(h, W_inr, b_r, P, PART,
      512, 512, 24576, 8192, 1536L, 524288L, 1024L, 512L, 1, 0);
  rnn_seq<<<dim3(16), dim3(1024), 0, stream>>>(P, Wh_r, h + 512, 524288L);
  // P = h1 @ W_in_rest[:,1] + b_rest[:,1]
  gemm_skinny<<<dim3(8,16,1), blk, 0, stream>>>(h + 512, W_inr + 262144, b_r + 512, P, PART,
      512, 512, 24576, 8192, 1536L, 524288L, 1024L, 512L, 1, 0);
  rnn_seq<<<dim3(16), dim3(1024), 0, stream>>>(P, Wh_r + 262144, h + 1024, 524288L);
  // FF1: gelu(cat @ W_ff1 + b_ff1)
  gemm_skinny<<<dim3(32,16,1), blk, 0, stream>>>(h, W_ff1, b_ff1, FF, PART,
      2048, 1536, 24576, 32768, 1536L, 3145728L, 2048L, 2048L, 1, 2);
  // FF2 (split-2): ENC = FF @ W_ff2 + b_ff2
  gemm_skinny<<<dim3(8,16,2), blk, 0, stream>>>(FF, W_ff2, b_ff2, ENC, PART,
      512, 2048, 32768, 8192, 2048L, 1048576L, 512L, 512L, 2, 0);
  reduce_ep<<<dim3(4096), blk, 0, stream>>>(PART, b_ff2, ENC,
      2, 512, 8192, 512L, 512L, 0, 16*128*512, 16);
  // decoder: Z0 = tanh(ENC @ W_d0 + b_d0)   (split-8)
  gemm_skinny<<<dim3(32,1,8), blk, 0, stream>>>(ENC, W_d0, b_d0, Z0, PART,
      2048, 8192, 8192, 2048, 0L, 0L, 0L, 0L, 8, 0);
  reduce_ep<<<dim3(1024), blk, 0, stream>>>(PART, b_d0, Z0,
      8, 2048, 2048, 0L, 0L, 1, 128*2048, 1);
  // Z1 = tanh(Z0 @ W_dmid[0] + b_dmid[0])
  gemm_skinny<<<dim3(32,1,8), blk, 0, stream>>>(Z0, W_dmid, b_dmid, Z1, PART,
      2048, 2048, 2048, 2048, 0L, 0L, 0L, 0L, 8, 0);
  reduce_ep<<<dim3(1024), blk, 0, stream>>>(PART, b_dmid, Z1,
      8, 2048, 2048, 0L, 0L, 1, 128*2048, 1);
  // Z2 = tanh(Z1 @ W_dmid[1] + b_dmid[1])
  gemm_skinny<<<dim3(32,1,8), blk, 0, stream>>>(Z1, W_dmid + 4194304, b_dmid + 2048, Z2, PART,
      2048, 2048, 2048, 2048, 0L, 0L, 0L, 0L, 8, 0);
  reduce_ep<<<dim3(1024), blk, 0, stream>>>(PART, b_dmid + 2048, Z2,
      8, 2048, 2048, 0L, 0L, 1, 128*2048, 1);
  // Y = Z2 @ W_dout + b_dout -> d_out [1,128,1024]
  gemm_skinny<<<dim3(16,1,8), blk, 0, stream>>>(Z2, W_dout, b_dout, (float*)d_out, PART,
      1024, 2048, 2048, 1024, 0L, 0L, 0L, 0L, 8, 0);
  reduce_ep<<<dim3(512), blk, 0, stream>>>(PART, b_dout, (float*)d_out,
      8, 1024, 1024, 0L, 0L, 0, 128*1024, 1);
}

// Round 10
// 1192.329 us; speedup vs baseline: 1.1742x; 1.1742x over previous
//
#include <hip/hip_runtime.h>
#include <hip/hip_bf16.h>
#include <hip/hip_fp16.h>

#define E_ 16
#define T_ 128

typedef _Float16 h2_t __attribute__((ext_vector_type(2)));
typedef _Float16 half4_t __attribute__((ext_vector_type(4)));
typedef _Float16 half8_t __attribute__((ext_vector_type(8)));
typedef float f32x4 __attribute__((ext_vector_type(4)));

__device__ __forceinline__ float fdot2u(uint32_t w, uint32_t h, float acc) {
#if __has_builtin(__builtin_amdgcn_fdot2)
  return __builtin_amdgcn_fdot2(__builtin_bit_cast(h2_t, w),
                                __builtin_bit_cast(h2_t, h), acc, false);
#else
  h2_t wv = __builtin_bit_cast(h2_t, w), hv = __builtin_bit_cast(h2_t, h);
  return acc + (float)wv.x * (float)hv.x + (float)wv.y * (float)hv.y;
#endif
}

__device__ __forceinline__ uint32_t rdlane(uint32_t v, int l) {
  return (uint32_t)__builtin_amdgcn_readlane((int)v, l);
}

__device__ __forceinline__ uint32_t packh2(float a, float b) {
  h2_t p; p.x = (_Float16)a; p.y = (_Float16)b;
  return __builtin_bit_cast(uint32_t, p);
}

__device__ __forceinline__ float apply_act(float v, int act) {
  if (act == 1) return tanhf(v);
  if (act == 2) { // jax.nn.gelu approximate=True
    const float c = 0.7978845608028654f;
    return 0.5f * v * (1.0f + tanhf(c * (v + 0.044715f * v * v * v)));
  }
  return v;
}

// ---- MFMA GEMM: C[128,N] = act(A[128,K] @ W[K,N] + bias), e-batched (grid.y),
// split-K (grid.z). fp32 inputs converted to fp16 on the fly (11-bit mantissa,
// fp32 accumulate -> ~1e-3 added error). M=128 exactly: every weight read once,
// so the kernel is weight-traffic-bound (409 MB total -> ~65 us HBM floor for
// the whole chain). Block 256 thr = 4 waves, 2x2 wave grid, 64x64 C per wave,
// 4x4 frags of v_mfma_f32_16x16x32_f16, BK=32.
// A staged in LDS as fp16, row stride 40 halves (80 B): 16 lanes hit 2-way
// bank aliasing max (free, m136). B-frags read direct from global: for fixed j
// lanes 0-15 read 16 consecutive fp32 = 64 B coalesced segments; each B chunk
// re-read by 2 row-waves (L1-served).
// Fragment layouts (AMD matrix-cores mapping, K=32 extension):
//   A: row = lane&15, k = (lane>>4)*8 + j
//   B: col = lane&15, k = (lane>>4)*8 + j
//   C: col = lane&15, row = (lane>>4)*4 + reg   [m89-verified]
__global__ void __launch_bounds__(256) gemm_mfma(
    const float* __restrict__ A, const float* __restrict__ W,
    const float* __restrict__ bias, float* __restrict__ C, float* __restrict__ part,
    int N, int K, int lda, int ldc,
    long sAe, long sWe, long sBe, long sCe,
    int S, int act)
{
  int n0 = blockIdx.x * 128;
  int e  = blockIdx.y;
  int s  = blockIdx.z;
  const float* Ae = A + (long)e * sAe;
  const float* We = W + (long)e * sWe;
  int kper = K / S;
  int kb = s * kper, ke2 = kb + kper;

  __shared__ _Float16 As[128 * 40];   // 10,240 B

  int tid  = threadIdx.x;
  int lane = tid & 63;
  int w    = tid >> 6;
  int wm   = (w >> 1) * 64;           // wave's row base within 128
  int wn   = (w & 1) * 64;            // wave's col base within 128
  int l16  = lane & 15;
  int lk   = lane >> 4;               // 0..3

  f32x4 acc[4][4];
  #pragma unroll
  for (int i = 0; i < 4; ++i)
    #pragma unroll
    for (int j = 0; j < 4; ++j)
      acc[i][j] = (f32x4){0.f, 0.f, 0.f, 0.f};

  for (int k0 = kb; k0 < ke2; k0 += 32) {
    __syncthreads();   // previous iteration's As reads complete
    #pragma unroll
    for (int i = 0; i < 4; ++i) {
      int idx = tid + 256 * i;
      int row = idx >> 3, k4 = idx & 7;
      float4 a4 = *(const float4*)(Ae + (long)row * lda + k0 + k4 * 4);
      half4_t hv;
      hv.x = (_Float16)a4.x; hv.y = (_Float16)a4.y;
      hv.z = (_Float16)a4.z; hv.w = (_Float16)a4.w;
      *(half4_t*)(&As[row * 40 + k4 * 4]) = hv;   // ds_write_b64, 8B aligned
    }
    __syncthreads();
    #pragma unroll
    for (int nt = 0; nt < 4; ++nt) {
      int ncol = n0 + wn + nt * 16 + l16;
      const float* Wc = We + (long)(k0 + lk * 8) * N + ncol;
      half8_t b;
      #pragma unroll
      for (int j = 0; j < 8; ++j) b[j] = (_Float16)Wc[(long)j * N];
      #pragma unroll
      for (int mt = 0; mt < 4; ++mt) {
        half8_t a = *(const half8_t*)(&As[(wm + mt * 16 + l16) * 40 + lk * 8]);
        acc[mt][nt] = __builtin_amdgcn_mfma_f32_16x16x32_f16(a, b, acc[mt][nt], 0, 0, 0);
      }
    }
  }

  if (S == 1) {
    #pragma unroll
    for (int mt = 0; mt < 4; ++mt)
      #pragma unroll
      for (int nt = 0; nt < 4; ++nt) {
        int col = n0 + wn + nt * 16 + l16;
        float bv = bias[(long)e * sBe + col];
        #pragma unroll
        for (int r = 0; r < 4; ++r) {
          int row = wm + mt * 16 + lk * 4 + r;
          C[(long)e * sCe + (long)row * ldc + col] = apply_act(acc[mt][nt][r] + bv, act);
        }
      }
  } else {
    float* pp = part + ((long)(s * gridDim.y + e) * 128) * N;
    #pragma unroll
    for (int mt = 0; mt < 4; ++mt)
      #pragma unroll
      for (int nt = 0; nt < 4; ++nt) {
        int col = n0 + wn + nt * 16 + l16;
        #pragma unroll
        for (int r = 0; r < 4; ++r) {
          int row = wm + mt * 16 + lk * 4 + r;
          pp[(long)row * N + col] = acc[mt][nt][r];
        }
      }
  }
}

// reduce split-K partials + bias + act -> C
__global__ void __launch_bounds__(256) reduce_ep(
    const float* __restrict__ part, const float* __restrict__ bias, float* __restrict__ C,
    int S, int N, int ldc, long sBe, long sCe, int act, int total, int Eb)
{
  int idx = blockIdx.x * 256 + threadIdx.x;
  if (idx >= total) return;
  int n = idx % N;
  int r = (idx / N) & 127;
  int e = idx / (N * 128);
  long sstride = (long)Eb * 128 * N;
  float v = 0.f;
  for (int s = 0; s < S; ++s) v += part[s * sstride + ((long)e * 128 + r) * N + n];
  v = apply_act(v + bias[(long)e * sBe + n], act);
  C[(long)e * sCe + (long)r * ldc + n] = v;
}

// ---- sequential RNN layer: h[t] = tanh(P[t] + h[t-1] @ Wh) ----
// (unchanged from round 8 — 295 us/layer local optimum; the compiler caps
// VGPRs at 65536/block_threads regardless of launch_bounds/waves_per_eu/
// num_vgpr/static-LDS, so the 92-pair weight block partially spills and the
// kernel is scratch-load-latency-bound. Left as-is this round.)
#define RNN_NV 46   // kpl in VGPRs (x2 cols = 92 regs)
#define RNN_NG 9    // uint4 LDS groups (18 kpl -> 36 uints/thread)

__global__ void
__attribute__((amdgpu_flat_work_group_size(1024, 1024)))
__attribute__((amdgpu_waves_per_eu(4, 4)))
__attribute__((amdgpu_num_vgpr(128)))
rnn_seq(
    const float* __restrict__ P,     // [T][E][512], pre-activation incl. bias
    const float* __restrict__ Wh,    // + e*sWe : [512][512]
    float* __restrict__ H,           // (t*E+e)*1536 + col  (layer offset applied by caller)
    long sWe)
{
  __shared__ uint32_t lw[RNN_NG * 4096];   // 147,456 B
  __shared__ uint32_t hbuf[256];           //   1,024 B (512 fp16)
  __shared__ float    red[3 * 512];        //   6,144 B

  int tid  = threadIdx.x;
  int lane = tid & 63;
  int wid  = tid >> 6;
  int kq   = wid >> 2;                 // K-quarter 0..3 (wave-uniform)
  int colg = wid & 3;
  int c0   = colg * 128 + lane * 2;    // this thread's two columns
  int e    = blockIdx.x;

  const float* W = Wh + (long)e * sWe;  // element (k,c) at W[k*512 + c]

  uint32_t w0[RNN_NV], w1[RNN_NV];
  #pragma unroll
  for (int q = 0; q < RNN_NV; ++q) {
    int k = kq * 128 + 2 * q;
    float2 ra = *(const float2*)(W + (long)k * 512 + c0);
    float2 rb = *(const float2*)(W + (long)(k + 1) * 512 + c0);
    w0[q] = packh2(ra.x, rb.x);
    w1[q] = packh2(ra.y, rb.y);
  }
  for (int g = 0; g < RNN_NG; ++g) {
    int k = kq * 128 + 2 * (RNN_NV + 2 * g);
    float2 ra = *(const float2*)(W + (long)(k + 0) * 512 + c0);
    float2 rb = *(const float2*)(W + (long)(k + 1) * 512 + c0);
    float2 rc = *(const float2*)(W + (long)(k + 2) * 512 + c0);
    float2 rd = *(const float2*)(W + (long)(k + 3) * 512 + c0);
    uint4 v;
    v.x = packh2(ra.x, rb.x);
    v.y = packh2(ra.y, rb.y);
    v.z = packh2(rc.x, rd.x);
    v.w = packh2(rc.y, rd.y);
    *(uint4*)(lw + ((long)g * 1024 + tid) * 4) = v;
  }
  if (tid < 256) hbuf[tid] = 0;   // h(-1) = 0
  __syncthreads();

  for (int t = 0; t < T_; ++t) {
    float2 pv = make_float2(0.f, 0.f);
    if (kq == 0) pv = *(const float2*)(P + ((long)t * E_ + e) * 512 + c0);
    uint32_t hr = hbuf[kq * 64 + lane];
    float a0 = 0.f, a1 = 0.f;
    #pragma unroll
    for (int L = 0; L < RNN_NV; ++L) {
      uint32_t hb = rdlane(hr, L);
      a0 = fdot2u(w0[L], hb, a0);
      a1 = fdot2u(w1[L], hb, a1);
    }
    #pragma unroll
    for (int g = 0; g < RNN_NG; ++g) {
      uint4 v = *(const uint4*)(lw + (g * 1024 + tid) * 4);
      uint32_t hb0 = rdlane(hr, RNN_NV + 2 * g);
      uint32_t hb1 = rdlane(hr, RNN_NV + 2 * g + 1);
      a0 = fdot2u(v.x, hb0, a0);
      a1 = fdot2u(v.y, hb0, a1);
      a0 = fdot2u(v.z, hb1, a0);
      a1 = fdot2u(v.w, hb1, a1);
    }
    if (kq) *(float2*)(red + (kq - 1) * 512 + c0) = make_float2(a0, a1);
    __syncthreads();
    if (kq == 0) {
      float v0 = a0 + red[c0]     + red[512 + c0]     + red[1024 + c0]     + pv.x;
      float v1 = a1 + red[c0 + 1] + red[512 + c0 + 1] + red[1024 + c0 + 1] + pv.y;
      v0 = tanhf(v0); v1 = tanhf(v1);
      *(float2*)(H + ((long)t * E_ + e) * 1536 + c0) = make_float2(v0, v1);
      hbuf[colg * 64 + lane] = packh2(v0, v1);
    }
    __syncthreads();
  }
}

extern "C" void kernel_launch(void* const* d_in, const int* in_sizes, int n_in,
                              void* d_out, int out_size, void* d_ws, size_t ws_size,
                              hipStream_t stream)
{
  const float* x      = (const float*)d_in[0];
  const float* W_in0  = (const float*)d_in[1];
  const float* Wh0    = (const float*)d_in[2];
  const float* b0     = (const float*)d_in[3];
  const float* W_inr  = (const float*)d_in[4];
  const float* Wh_r   = (const float*)d_in[5];
  const float* b_r    = (const float*)d_in[6];
  const float* W_ff1  = (const float*)d_in[7];
  const float* b_ff1  = (const float*)d_in[8];
  const float* W_ff2  = (const float*)d_in[9];
  const float* b_ff2  = (const float*)d_in[10];
  const float* W_d0   = (const float*)d_in[11];
  const float* b_d0   = (const float*)d_in[12];
  const float* W_dmid = (const float*)d_in[13];
  const float* b_dmid = (const float*)d_in[14];
  const float* W_dout = (const float*)d_in[15];
  const float* b_dout = (const float*)d_in[16];
  float* ws = (float*)d_ws;

  // workspace layout (floats)
  float* h    = ws;                    // [T][E][3][512]  3,145,728
  float* P    = ws + 3145728;          // [T][E][512]     1,048,576
  float* FF   = ws + 4194304;          // [T][E][2048]    4,194,304
  float* ENC  = ws + 8388608;          // [T][E*512]      1,048,576
  float* Z0   = ws + 9437184;          // [128][2048]       262,144
  float* Z1   = ws + 9699328;
  float* Z2   = ws + 9961472;
  float* PART = ws + 10223616;         // split-K partials 2,097,152

  (void)in_sizes; (void)n_in; (void)out_size; (void)ws_size;

  dim3 blk(256);

  // P = x @ W_in0 + b0
  gemm_mfma<<<dim3(4,16,1), blk, 0, stream>>>(x, W_in0, b0, P, PART,
      512, 32, 32, 8192, 0L, 16384L, 512L, 512L, 1, 0);
  // layer 0 recurrence
  rnn_seq<<<dim3(16), dim3(1024), 0, stream>>>(P, Wh0, h, 262144L);
  // P = h0 @ W_in_rest[:,0] + b_rest[:,0]
  gemm_mfma<<<dim3(4,16,1), blk, 0, stream>>>(h, W_inr, b_r, P, PART,
      512, 512, 24576, 8192, 1536L, 524288L, 1024L, 512L, 1, 0);
  rnn_seq<<<dim3(16), dim3(1024), 0, stream>>>(P, Wh_r, h + 512, 524288L);
  // P = h1 @ W_in_rest[:,1] + b_rest[:,1]
  gemm_mfma<<<dim3(4,16,1), blk, 0, stream>>>(h + 512, W_inr + 262144, b_r + 512, P, PART,
      512, 512, 24576, 8192, 1536L, 524288L, 1024L, 512L, 1, 0);
  rnn_seq<<<dim3(16), dim3(1024), 0, stream>>>(P, Wh_r + 262144, h + 1024, 524288L);
  // FF1: gelu(cat @ W_ff1 + b_ff1)
  gemm_mfma<<<dim3(16,16,1), blk, 0, stream>>>(h, W_ff1, b_ff1, FF, PART,
      2048, 1536, 24576, 32768, 1536L, 3145728L, 2048L, 2048L, 1, 2);
  // FF2 (split-2): ENC = FF @ W_ff2 + b_ff2
  gemm_mfma<<<dim3(4,16,2), blk, 0, stream>>>(FF, W_ff2, b_ff2, ENC, PART,
      512, 2048, 32768, 8192, 2048L, 1048576L, 512L, 512L, 2, 0);
  reduce_ep<<<dim3(4096), blk, 0, stream>>>(PART, b_ff2, ENC,
      2, 512, 8192, 512L, 512L, 0, 16*128*512, 16);
  // decoder: Z0 = tanh(ENC @ W_d0 + b_d0)   (split-8)
  gemm_mfma<<<dim3(16,1,8), blk, 0, stream>>>(ENC, W_d0, b_d0, Z0, PART,
      2048, 8192, 8192, 2048, 0L, 0L, 0L, 0L, 8, 0);
  reduce_ep<<<dim3(1024), blk, 0, stream>>>(PART, b_d0, Z0,
      8, 2048, 2048, 0L, 0L, 1, 128*2048, 1);
  // Z1 = tanh(Z0 @ W_dmid[0] + b_dmid[0])
  gemm_mfma<<<dim3(16,1,8), blk, 0, stream>>>(Z0, W_dmid, b_dmid, Z1, PART,
      2048, 2048, 2048, 2048, 0L, 0L, 0L, 0L, 8, 0);
  reduce_ep<<<dim3(1024), blk, 0, stream>>>(PART, b_dmid, Z1,
      8, 2048, 2048, 0L, 0L, 1, 128*2048, 1);
  // Z2 = tanh(Z1 @ W_dmid[1] + b_dmid[1])
  gemm_mfma<<<dim3(16,1,8), blk, 0, stream>>>(Z1, W_dmid + 4194304, b_dmid + 2048, Z2, PART,
      2048, 2048, 2048, 2048, 0L, 0L, 0L, 0L, 8, 0);
  reduce_ep<<<dim3(1024), blk, 0, stream>>>(PART, b_dmid + 2048, Z2,
      8, 2048, 2048, 0L, 0L, 1, 128*2048, 1);
  // Y = Z2 @ W_dout + b_dout -> d_out [1,128,1024]
  gemm_mfma<<<dim3(8,1,8), blk, 0, stream>>>(Z2, W_dout, b_dout, (float*)d_out, PART,
      1024, 2048, 2048, 1024, 0L, 0L, 0L, 0L, 8, 0);
  reduce_ep<<<dim3(512), blk, 0, stream>>>(PART, b_dout, (float*)d_out,
      8, 1024, 1024, 0L, 0L, 0, 128*1024, 1);
}